// Round 10
// baseline (96.145 us; speedup 1.0000x reference)
//
#include <hip/hip_runtime.h>
#include <hip/hip_bf16.h>

// B=2, S=2048, D=512, H=8, DH=64, P=10, M=4096
// Linear (no-softmax) relative attention via associativity:
//   out1 = Q(K^T V) + r0*Vpre + r20*Vsuf + band(Rq)·V
//   out2 = CS @ rel_v, CS = {bin0, band S, bin20}, bins via K prefix dots.

typedef __attribute__((ext_vector_type(8)))  short  short8;
typedef __attribute__((ext_vector_type(4)))  short  short4v;
typedef __attribute__((ext_vector_type(16))) float  f32x16;
typedef __attribute__((ext_vector_type(8)))  __bf16 bf16x8;

#define DEV static __device__ __forceinline__

constexpr float INV_SCALE = 0.044194173824159216f; // 1/sqrt(512)

DEV unsigned short f2bs(float f){ __hip_bfloat16 h = __float2bfloat16(f); unsigned short u; __builtin_memcpy(&u,&h,2); return u; }
DEV short f2b(float f){ return (short)f2bs(f); }
DEV float b2f(short s){ unsigned u = ((unsigned)(unsigned short)s)<<16; float f; __builtin_memcpy(&f,&u,4); return f; }
DEV bf16x8 ld8s(const short* p){ return __builtin_bit_cast(bf16x8, *(const short8*)p); }
DEV f32x16 z16(){ f32x16 z;
#pragma unroll
  for (int i=0;i<16;++i) z[i]=0.f;
  return z; }
DEV f32x16 mfma32(bf16x8 a, bf16x8 b, f32x16 c){ return __builtin_amdgcn_mfma_f32_32x32x16_bf16(a,b,c,0,0,0); }

// ---------------------------------------------------------------------------
// Weight transpose + cvt: WT[n][k] = bf16(W[k][n])
// ---------------------------------------------------------------------------
struct WtArgs { const float* W[4]; short* O[4]; };

__global__ __launch_bounds__(256) void wt_kernel(WtArgs args){
  const float* W = args.W[blockIdx.z];
  short* O = args.O[blockIdx.z];
  const int kt = blockIdx.x*64, nt = blockIdx.y*64;
  __shared__ float t[64][65];
  const int tid = threadIdx.x;
#pragma unroll
  for (int p=0;p<4;++p){
    int idx = p*1024 + tid*4; int r = idx>>6, c = idx&63;
    float4 v = *(const float4*)(W + (size_t)(kt+r)*512 + nt + c);
    t[r][c]=v.x; t[r][c+1]=v.y; t[r][c+2]=v.z; t[r][c+3]=v.w;
  }
  __syncthreads();
#pragma unroll
  for (int p=0;p<4;++p){
    int idx = p*1024 + tid*4; int n = idx>>6, k = idx&63;
    short4v o = { f2b(t[k][n]), f2b(t[k+1][n]), f2b(t[k+2][n]), f2b(t[k+3][n]) };
    *(short4v*)(O + (size_t)(nt+n)*512 + kt + k) = o;
  }
}

// ---------------------------------------------------------------------------
// GEMM: C[4096][512] = A @ W + bias.  BM=128, BN=128, BK=64, 4 waves.
// Wave owns 32 rows x 128 cols (4 f32x16 accs). A-redundancy = 512/128 = 4x.
// If Xt != nullptr (K/V projections): also emit head-transposed tiles
// Xt[dh][s] for the 2 heads this block covers (LDS round-trip epilogue).
// ---------------------------------------------------------------------------
template<bool AF32, bool OUTB16>
DEV void gemm_body(const void* A, const short* BT, const float* bias, void* C,
                   int m0, int n0, short* Alds, short* Blds, short* Xt){
  const int tid = threadIdx.x, lane = tid&63, wid = tid>>6, lo5 = lane&31, hi = lane>>5;
  f32x16 acc0 = z16(), acc1 = z16(), acc2 = z16(), acc3 = z16();
  for (int kt=0; kt<8; ++kt){
    const int k0 = kt*64;
    __syncthreads();
    {
      const int rr = tid>>3, c = tid&7;
#pragma unroll
      for (int p=0;p<4;++p){
        int row = p*32 + rr;
        short8 v;
        if (AF32){
          const float* ap = (const float*)A + (size_t)(m0+row)*512 + k0 + c*8;
          float4 x = *(const float4*)ap; float4 y = *(const float4*)(ap+4);
          v = short8{ f2b(x.x),f2b(x.y),f2b(x.z),f2b(x.w), f2b(y.x),f2b(y.y),f2b(y.z),f2b(y.w) };
        } else {
          v = *(const short8*)((const short*)A + (size_t)(m0+row)*512 + k0 + c*8);
        }
        *(short8*)&Alds[row*64 + ((c ^ (row&7))*8)] = v;
      }
#pragma unroll
      for (int p=0;p<4;++p){
        int row = p*32 + rr;   // n-index within tile
        short8 v = *(const short8*)(BT + (size_t)(n0+row)*512 + k0 + c*8);
        *(short8*)&Blds[row*64 + ((c ^ (row&7))*8)] = v;
      }
    }
    __syncthreads();
#pragma unroll
    for (int da=0; da<4; ++da){
      const int arow = wid*32 + lo5;
      bf16x8 af = ld8s(&Alds[arow*64 + (((2*da+hi) ^ (arow&7))*8)]);
      const int b0r = lo5, b1r = 32+lo5, b2r = 64+lo5, b3r = 96+lo5;
      acc0 = mfma32(af, ld8s(&Blds[b0r*64 + (((2*da+hi) ^ (b0r&7))*8)]), acc0);
      acc1 = mfma32(af, ld8s(&Blds[b1r*64 + (((2*da+hi) ^ (b1r&7))*8)]), acc1);
      acc2 = mfma32(af, ld8s(&Blds[b2r*64 + (((2*da+hi) ^ (b2r&7))*8)]), acc2);
      acc3 = mfma32(af, ld8s(&Blds[b3r*64 + (((2*da+hi) ^ (b3r&7))*8)]), acc3);
    }
  }
  const float bv0 = bias[n0 + lo5],      bv1 = bias[n0 + 32 + lo5];
  const float bv2 = bias[n0 + 64 + lo5], bv3 = bias[n0 + 96 + lo5];
#pragma unroll
  for (int r=0;r<16;++r){
    const int m = m0 + wid*32 + (r&3) + 8*(r>>2) + 4*hi;
    if (OUTB16){
      ((short*)C)[(size_t)m*512 + n0 + lo5]       = f2b(acc0[r] + bv0);
      ((short*)C)[(size_t)m*512 + n0 + 32 + lo5]  = f2b(acc1[r] + bv1);
      ((short*)C)[(size_t)m*512 + n0 + 64 + lo5]  = f2b(acc2[r] + bv2);
      ((short*)C)[(size_t)m*512 + n0 + 96 + lo5]  = f2b(acc3[r] + bv3);
    } else {
      ((float*)C)[(size_t)m*512 + n0 + lo5]       = acc0[r] + bv0;
      ((float*)C)[(size_t)m*512 + n0 + 32 + lo5]  = acc1[r] + bv1;
      ((float*)C)[(size_t)m*512 + n0 + 64 + lo5]  = acc2[r] + bv2;
      ((float*)C)[(size_t)m*512 + n0 + 96 + lo5]  = acc3[r] + bv3;
    }
  }
  if (Xt){
    // head-transpose epilogue: 2 heads (cols 0-63 -> hh=0, 64-127 -> hh=1)
#pragma unroll
    for (int hh=0; hh<2; ++hh){
      __syncthreads();              // Alds free (MFMA reads / prev round done)
#pragma unroll
      for (int r=0;r<16;++r){
        const int ml = wid*32 + (r&3) + 8*(r>>2) + 4*hi;
        if (hh == 0){
          Alds[ml*64 + lo5]      = f2b(acc0[r] + bv0);
          Alds[ml*64 + 32 + lo5] = f2b(acc1[r] + bv1);
        } else {
          Alds[ml*64 + lo5]      = f2b(acc2[r] + bv2);
          Alds[ml*64 + 32 + lo5] = f2b(acc3[r] + bv3);
        }
      }
      __syncthreads();
      const int dh = tid & 63, chq = tid >> 6;    // thread owns 32 s of row dh
      short* xrow = Xt + (size_t)hh*64*2048 + (size_t)dh*2048 + chq*32;
#pragma unroll
      for (int cp=0; cp<4; ++cp){
        short8 t;
#pragma unroll
        for (int e=0;e<8;++e) t[e] = Alds[(chq*32 + cp*8 + e)*64 + dh];
        *(short8*)(xrow + cp*8) = t;
      }
    }
  }
}

struct ProjArgs { const float* A[3]; const short* BT[3]; const float* bias[3]; short* C[3]; short* XT[3]; };

__global__ __launch_bounds__(256) void proj_gemm(ProjArgs args){
  __shared__ short Alds[128*64];
  __shared__ short Blds[128*64];
  const int z = blockIdx.z;
  const int m0 = blockIdx.x*128, n0 = blockIdx.y*128;
  short* xt = nullptr;
  if (args.XT[z]){
    const int b = m0>>11, h0 = n0>>6, s0 = m0&2047;
    xt = args.XT[z] + ((size_t)(b*8+h0)*64)*2048 + s0;
  }
  gemm_body<true,true>(args.A[z], args.BT[z], args.bias[z], args.C[z],
                       m0, n0, Alds, Blds, xt);
}

__global__ __launch_bounds__(256) void out_gemm(const short* A, const short* BT, const float* bias, float* C){
  __shared__ short Alds[128*64];
  __shared__ short Blds[128*64];
  gemm_body<false,false>(A, BT, bias, C, blockIdx.x*128, blockIdx.y*128, Alds, Blds, nullptr);
}

// ---------------------------------------------------------------------------
// Merged kv-partial + prefix kernel. Grid = 192 blocks, 256 threads.
//  blk <  128: KVpart[(bh*8+ch)][j*64+i] = Σ_{s in chunk} K[s][i]V[s][j] (fp32)
//  blk >= 128: prefix sums; idx = blk-128: bh=idx>>2, z=(idx>>1)&1, dhalf=idx&1
// ---------------------------------------------------------------------------
__global__ __launch_bounds__(256) void kvpfx_kernel(const short* Kp, const short* Vp,
    const short* Kt, const short* Vt, float* KVpart, float* KP, float* VP){
  __shared__ float shmem[4*64*64];   // 64 KB, aliased per branch
  const int blk = blockIdx.x, tid = threadIdx.x;

  if (blk < 128){
    const int bh = blk>>3, ch = blk&7;
    const int lane = tid&63, wid = tid>>6, lo5 = lane&31, hi = lane>>5;
    const short* Ktb = Kt + (size_t)bh*64*2048;
    const short* Vtb = Vt + (size_t)bh*64*2048;
    f32x16 a00=z16(), a01=z16(), a10=z16(), a11=z16();
    const int sb = ch*256 + wid*64;
    for (int s = sb; s < sb+64; s += 16){
      bf16x8 ka = ld8s(Ktb + (size_t)lo5*2048 + s + hi*8);
      bf16x8 kb = ld8s(Ktb + (size_t)(32+lo5)*2048 + s + hi*8);
      bf16x8 va = ld8s(Vtb + (size_t)lo5*2048 + s + hi*8);
      bf16x8 vb = ld8s(Vtb + (size_t)(32+lo5)*2048 + s + hi*8);
      a00 = mfma32(ka, va, a00);
      a01 = mfma32(ka, vb, a01);
      a10 = mfma32(kb, va, a10);
      a11 = mfma32(kb, vb, a11);
    }
    float (*red)[64][64] = (float(*)[64][64])shmem;
#pragma unroll
    for (int r=0;r<16;++r){
      int ir = (r&3) + 8*(r>>2) + 4*hi;
      red[wid][ir][lo5]        = a00[r];
      red[wid][ir][32+lo5]     = a01[r];
      red[wid][32+ir][lo5]     = a10[r];
      red[wid][32+ir][32+lo5]  = a11[r];
    }
    __syncthreads();
    float* dst = KVpart + (size_t)(bh*8+ch)*4096;
    for (int e = tid; e < 4096; e += 256){
      int j = e>>6, i = e&63;
      dst[e] = red[0][i][j] + red[1][i][j] + red[2][i][j] + red[3][i][j];  // KVpart[j][i]
    }
  } else {
    const int idx = blk - 128;
    const int bh = idx>>2, z = (idx>>1)&1, dhalf = idx&1;
    const int b = bh>>3, h = bh&7;
    const short* X = (z ? Vp : Kp) + (size_t)b*2048*512 + h*64 + dhalf*32;
    float* P = (z ? VP : KP) + (size_t)bh*2048*64 + dhalf*32;
    const int dg = tid & 3;          // d-group within half: d = dg*8..dg*8+7
    const int ch = tid >> 2;         // chunk: rows ch*32 .. +31
    float (*tot)[4][8] = (float(*)[4][8])shmem;  // [64][4][8]

    const short* xp = X + (size_t)(ch*32)*512 + dg*8;
    float acc[8];
#pragma unroll
    for (int j=0;j<8;++j) acc[j]=0.f;
    for (int i=0;i<32;++i){
      short8 v = *(const short8*)(xp + (size_t)i*512);
#pragma unroll
      for (int j=0;j<8;++j) acc[j] += b2f(v[j]);
    }
#pragma unroll
    for (int j=0;j<8;++j) tot[ch][dg][j] = acc[j];
    __syncthreads();

    float run[8];
#pragma unroll
    for (int j=0;j<8;++j) run[j]=0.f;
    for (int cc=0; cc<ch; ++cc){
      float4 a = *(const float4*)&tot[cc][dg][0];
      float4 c4 = *(const float4*)&tot[cc][dg][4];
      run[0]+=a.x; run[1]+=a.y; run[2]+=a.z; run[3]+=a.w;
      run[4]+=c4.x; run[5]+=c4.y; run[6]+=c4.z; run[7]+=c4.w;
    }
    float* pp = P + (size_t)(ch*32)*64 + dg*8;
    for (int i=0;i<32;++i){
      short8 v = *(const short8*)(xp + (size_t)i*512);
#pragma unroll
      for (int j=0;j<8;++j) run[j] += b2f(v[j]);
      float4 o0 = { run[0], run[1], run[2], run[3] };
      float4 o1 = { run[4], run[5], run[6], run[7] };
      *(float4*)(pp + (size_t)i*64)     = o0;
      *(float4*)(pp + (size_t)i*64 + 4) = o1;
    }
  }
}

// ---------------------------------------------------------------------------
// attn2: per (qt, bh) block of 128 q rows, 4 waves x 32 q.
//  Prologue: reduce 8 fp32 KVpart chunks -> swizzled bf16 LDS tile KVl[j][i].
//  w1 = Q·KV + band(Rq)·V + r0*Vpre + r20*Vsuf
//  w2 = CS @ rel_v,  CS[q][j]: j=0 bin0, j=20 bin20 (prefix dots), j=1..19 band
// ---------------------------------------------------------------------------
__global__ __launch_bounds__(256) void attn2_kernel(const short* Qp, const short* Kp,
    const short* Vt, const float* KVpart, const float* KP, const float* VP,
    const float* relk_g, const float* relv_g, short* xb){
  const int qt = blockIdx.x, bh = blockIdx.y;
  const int b = bh>>3, h = bh&7;
  const int tid = threadIdx.x, lane = tid&63, wid = tid>>6, lo5 = lane&31, hi = lane>>5;
  const int q0 = qt*128, qw = q0 + wid*32;

  __shared__ float Rq[128*21];
  __shared__ short CS[128*32];
  __shared__ short RVT[64*32];
  __shared__ short KVl[64*64];

  for (int i=tid; i<2048; i+=256) ((int*)CS)[i] = 0;
  for (int i=tid; i<2048; i+=256){
    int d = i>>5, j = i&31;
    RVT[d*32 + (j ^ ((d&3)<<3))] = (j<21) ? f2b(relv_g[j*64+d]) : (short)0;
  }

  // KV reduction: thread owns (j = tid>>2, i0 = (tid&3)*16); swizzled store
  {
    const int j = tid>>2, i0 = (tid&3)*16;
    float acc[16];
#pragma unroll
    for (int t=0;t<16;++t) acc[t]=0.f;
#pragma unroll
    for (int c=0;c<8;++c){
      const float* p = KVpart + (size_t)(bh*8+c)*4096 + j*64 + i0;
#pragma unroll
      for (int t4=0;t4<4;++t4){
        float4 v = *(const float4*)(p + t4*4);
        acc[t4*4+0]+=v.x; acc[t4*4+1]+=v.y; acc[t4*4+2]+=v.z; acc[t4*4+3]+=v.w;
      }
    }
#pragma unroll
    for (int half=0; half<2; ++half){
      short8 o;
#pragma unroll
      for (int e=0;e<8;++e) o[e] = f2b(acc[half*8+e]);
      const int chunk = (i0>>3) + half;
      *(short8*)&KVl[j*64 + ((chunk ^ (j&7))*8)] = o;
    }
  }

  // Q fragments
  bf16x8 qf[4];
  {
    const short* Qrow = Qp + (size_t)(b*2048 + qw + lo5)*512 + h*64 + hi*8;
#pragma unroll
    for (int da=0;da<4;++da) qf[da] = ld8s(Qrow + da*16);
  }

  // Rq[q][j] = Q[q]·rel_k[j]
  {
    f32x16 rq = z16();
    const int jr = lo5 <= 20 ? lo5 : 20;
    const float* rp = relk_g + jr*64 + hi*8;
#pragma unroll
    for (int da=0;da<4;++da){
      const float* p = rp + da*16;
      float4 x = *(const float4*)p; float4 y = *(const float4*)(p+4);
      short8 rb = { f2b(x.x),f2b(x.y),f2b(x.z),f2b(x.w), f2b(y.x),f2b(y.y),f2b(y.z),f2b(y.w) };
      rq = mfma32(qf[da], __builtin_bit_cast(bf16x8, rb), rq);
    }
    if (lo5 <= 20){
#pragma unroll
      for (int r=0;r<16;++r){
        int qoff = (r&3) + 8*(r>>2) + 4*hi;
        Rq[(wid*32 + qoff)*21 + lo5] = rq[r];
      }
    }
  }
  __syncthreads();

  const int qrow = wid*32 + lo5;
  const int qg = q0 + qrow;

  f32x16 w1a = z16(), w1b = z16();

  // (a) Q·KV from swizzled LDS
  {
#pragma unroll
    for (int c=0;c<4;++c){
      const int r0i = lo5, r1i = 32+lo5, ck = 2*c+hi;
      bf16x8 b0v = ld8s(&KVl[r0i*64 + ((ck ^ (r0i&7))*8)]);
      bf16x8 b1v = ld8s(&KVl[r1i*64 + ((ck ^ (r1i&7))*8)]);
      w1a = mfma32(qf[c], b0v, w1a);
      w1b = mfma32(qf[c], b1v, w1b);
    }
  }

  // (b) band-PV
  {
    const short* Vg = Vt + (size_t)bh*64*2048;
#pragma unroll
    for (int c=0;c<4;++c){
      const int kb = qw - 16 + c*16;
      const int kbse = kb + hi*8;
      const int jb = kbse - (qw + lo5) + 10;
      short8 av;
#pragma unroll
      for (int e=0;e<8;++e){
        int j = jb + e, kk = kbse + e;
        int jc = j < 1 ? 1 : (j > 19 ? 19 : j);
        float rv = Rq[qrow*21 + jc];
        bool ok = (j>=1) && (j<=19) && (kk>=0) && (kk<2048);
        av[e] = ok ? f2b(rv) : (short)0;
      }
      bf16x8 af = __builtin_bit_cast(bf16x8, av);
      const int kc = kb < 0 ? 0 : (kb > 2048-16 ? 2048-16 : kb);
      bf16x8 v0 = ld8s(Vg + (size_t)lo5*2048 + kc + hi*8);
      bf16x8 v1 = ld8s(Vg + (size_t)(32+lo5)*2048 + kc + hi*8);
      w1a = mfma32(af, v0, w1a);
      w1b = mfma32(af, v1, w1b);
    }
  }

  // (c) prefix-V terms
  {
    const float* VPb = VP + (size_t)bh*2048*64;
    const float vt0 = VPb[(size_t)2047*64 + lo5];
    const float vt1 = VPb[(size_t)2047*64 + 32 + lo5];
#pragma unroll
    for (int r=0;r<16;++r){
      const int q_r = qw + (r&3) + 8*(r>>2) + 4*hi;
      const int ql = q_r - q0;
      const float r0q  = Rq[ql*21 + 0];
      const float r20q = Rq[ql*21 + 20];
      float p0=0.f, p1=0.f, s0=0.f, s1=0.f;
      if (q_r >= 10){
        const float* pr = VPb + (size_t)(q_r-10)*64;
        p0 = pr[lo5]; p1 = pr[32+lo5];
      }
      if (q_r <= 2037){
        const float* sr = VPb + (size_t)(q_r+9)*64;
        s0 = vt0 - sr[lo5]; s1 = vt1 - sr[32+lo5];
      }
      w1a[r] += r0q*p0 + r20q*s0;
      w1b[r] += r0q*p1 + r20q*s1;
    }
  }

  // (d) diagonal QK^T subtiles -> CS band (j=1..19)
  {
    const short* Kg = Kp + (size_t)b*2048*512 + h*64;
#pragma unroll
    for (int t3=0; t3<3; ++t3){
      const int kb = qw - 32 + t3*32;
      if (kb < 0 || kb >= 2048) continue;
      const short* Krow = Kg + (size_t)(kb + lo5)*512 + hi*8;
      f32x16 acc = z16();
#pragma unroll
      for (int da=0;da<4;++da) acc = mfma32(ld8s(Krow + da*16), qf[da], acc);
#pragma unroll
      for (int r=0;r<16;++r){
        const int krow = kb + (r&3) + 8*(r>>2) + 4*hi;
        const int j = krow - qg + 10;
        if (j >= 1 && j <= 19)
          CS[qrow*32 + (j ^ ((qrow&3)<<3))] = f2b(acc[r] + Rq[qrow*21 + j]);
      }
    }
  }

  // (e) bins via K-prefix dots; wave-uniform split (waves 0-1: bin0, 2-3: bin20)
  {
    const int half = tid >> 7, q_loc = tid & 127;
    const int q_g2 = q0 + q_loc;
    const short* Qr = Qp + (size_t)(b*2048 + q_g2)*512 + h*64;
    const float* KPb = KP + (size_t)bh*2048*64;
    float val = 0.f;
    if (half == 0){
      if (q_g2 >= 10){
        const float* Pr = KPb + (size_t)(q_g2-10)*64;
        float dot = 0.f;
#pragma unroll
        for (int ii=0; ii<8; ++ii){
          short8 qv = *(const short8*)(Qr + ii*8);
          float4 p0 = *(const float4*)(Pr + ii*8);
          float4 p1 = *(const float4*)(Pr + ii*8 + 4);
          dot += b2f(qv[0])*p0.x + b2f(qv[1])*p0.y + b2f(qv[2])*p0.z + b2f(qv[3])*p0.w
               + b2f(qv[4])*p1.x + b2f(qv[5])*p1.y + b2f(qv[6])*p1.z + b2f(qv[7])*p1.w;
        }
        val = dot + (float)(q_g2 - 9) * Rq[q_loc*21 + 0];
      }
      CS[q_loc*32 + (0 ^ ((q_loc&3)<<3))] = f2b(val);
    } else {
      if (q_g2 <= 2037){
        const float* Pt = KPb + (size_t)2047*64;
        const float* Pr = KPb + (size_t)(q_g2+9)*64;
        float dot = 0.f;
#pragma unroll
        for (int ii=0; ii<8; ++ii){
          short8 qv = *(const short8*)(Qr + ii*8);
          float4 p0 = *(const float4*)(Pr + ii*8);
          float4 t0 = *(const float4*)(Pt + ii*8);
          float4 p1 = *(const float4*)(Pr + ii*8 + 4);
          float4 t1 = *(const float4*)(Pt + ii*8 + 4);
          dot += b2f(qv[0])*(t0.x-p0.x) + b2f(qv[1])*(t0.y-p0.y)
               + b2f(qv[2])*(t0.z-p0.z) + b2f(qv[3])*(t0.w-p0.w)
               + b2f(qv[4])*(t1.x-p1.x) + b2f(qv[5])*(t1.y-p1.y)
               + b2f(qv[6])*(t1.z-p1.z) + b2f(qv[7])*(t1.w-p1.w);
        }
        val = dot + (float)(2038 - q_g2) * Rq[q_loc*21 + 20];
      }
      CS[q_loc*32 + (20 ^ ((q_loc&3)<<3))] = f2b(val);
    }
  }
  __syncthreads();

  // (f) w2 = CS @ RVT
  f32x16 w2a = z16(), w2b = z16();
#pragma unroll
  for (int c2=0;c2<2;++c2){
    const int arow = wid*32 + lo5;
    bf16x8 cf  = ld8s(&CS[arow*32 + ((16*c2 + 8*hi) ^ ((arow&3)<<3))]);
    const int d0 = lo5, d1 = 32 + lo5;
    bf16x8 rv0 = ld8s(&RVT[d0*32 + ((16*c2 + 8*hi) ^ ((d0&3)<<3))]);
    bf16x8 rv1 = ld8s(&RVT[d1*32 + ((16*c2 + 8*hi) ^ ((d1&3)<<3))]);
    w2a = mfma32(cf, rv0, w2a);
    w2b = mfma32(cf, rv1, w2b);
  }

  // (g) write xb
#pragma unroll
  for (int r=0;r<16;++r){
    const int q_r = qw + (r&3) + 8*(r>>2) + 4*hi;
    const size_t o = ((size_t)b*2048 + q_r)*512 + h*64;
    xb[o + lo5]      = f2b((w1a[r] + w2a[r]) * INV_SCALE);
    xb[o + 32 + lo5] = f2b((w1b[r] + w2b[r]) * INV_SCALE);
  }
}

// ---------------------------------------------------------------------------
extern "C" void kernel_launch(void* const* d_in, const int* in_sizes, int n_in,
                              void* d_out, int out_size, void* d_ws, size_t ws_size,
                              hipStream_t stream) {
  (void)in_sizes; (void)n_in; (void)out_size; (void)ws_size;
  const float* q    = (const float*)d_in[0];
  const float* k    = (const float*)d_in[1];
  const float* v    = (const float*)d_in[2];
  // d_in[3] = mask (no-op)
  const float* Wq   = (const float*)d_in[4];
  const float* bq   = (const float*)d_in[5];
  const float* Wk   = (const float*)d_in[6];
  const float* bk   = (const float*)d_in[7];
  const float* Wv   = (const float*)d_in[8];
  const float* bv   = (const float*)d_in[9];
  const float* W0   = (const float*)d_in[10];
  const float* b0   = (const float*)d_in[11];
  const float* relk = (const float*)d_in[12];
  const float* relv = (const float*)d_in[13];
  float* out = (float*)d_out;
  char* ws = (char*)d_ws;

  short* WTq = (short*)(ws);
  short* WTk = WTq + 512*512;
  short* WTv = WTk + 512*512;
  short* WT0 = WTv + 512*512;
  short* Qp  = (short*)(ws + ((size_t) 2<<20));
  short* Kp  = (short*)(ws + ((size_t) 6<<20));
  short* Vp  = (short*)(ws + ((size_t)10<<20));
  short* Vt  = (short*)(ws + ((size_t)14<<20));
  short* Kt  = (short*)(ws + ((size_t)18<<20));
  float* KVpart = (float*)(ws + ((size_t)22<<20)); // 2 MB (128 x 4096 fp32)
  float* KP  = (float*)(ws + ((size_t)24<<20));    // 8 MB
  float* VP  = (float*)(ws + ((size_t)32<<20));    // 8 MB
  short* xb  = (short*)(ws + ((size_t)40<<20));    // 4 MB

  WtArgs wa = { {Wq, Wk, Wv, W0}, {WTq, WTk, WTv, WT0} };
  wt_kernel<<<dim3(8,8,4), 256, 0, stream>>>(wa);

  ProjArgs pa = { {q, k, v}, {WTq, WTk, WTv}, {bq, bk, bv}, {Qp, Kp, Vp},
                  {nullptr, Kt, Vt} };
  proj_gemm<<<dim3(32,4,3), 256, 0, stream>>>(pa);

  kvpfx_kernel<<<192, 256, 0, stream>>>(Kp, Vp, Kt, Vt, KVpart, KP, VP);

  attn2_kernel<<<dim3(16,16), 256, 0, stream>>>(Qp, Kp, Vt, KVpart, KP, VP, relk, relv, xb);

  out_gemm<<<dim3(32,4), 256, 0, stream>>>(xb, WT0, b0, out);
}

// Round 11
// 81.157 us; speedup vs baseline: 1.1847x; 1.1847x over previous
//
#include <hip/hip_runtime.h>
#include <hip/hip_bf16.h>

// B=2, S=2048, D=512, H=8, DH=64, P=10, M=4096
// Linear (no-softmax) relative attention via associativity:
//   out1 = Q(K^T V) + r0*Vpre + r20*Vsuf + band(Rq)·V
//   out2 = CS @ rel_v, CS = {bin0, band S, bin20}, bins via K prefix dots.

typedef __attribute__((ext_vector_type(8)))  short  short8;
typedef __attribute__((ext_vector_type(4)))  short  short4v;
typedef __attribute__((ext_vector_type(16))) float  f32x16;
typedef __attribute__((ext_vector_type(8)))  __bf16 bf16x8;

#define DEV static __device__ __forceinline__

constexpr float INV_SCALE = 0.044194173824159216f; // 1/sqrt(512)

DEV unsigned short f2bs(float f){ __hip_bfloat16 h = __float2bfloat16(f); unsigned short u; __builtin_memcpy(&u,&h,2); return u; }
DEV short f2b(float f){ return (short)f2bs(f); }
DEV float b2f(short s){ unsigned u = ((unsigned)(unsigned short)s)<<16; float f; __builtin_memcpy(&f,&u,4); return f; }
DEV bf16x8 ld8s(const short* p){ return __builtin_bit_cast(bf16x8, *(const short8*)p); }
DEV f32x16 z16(){ f32x16 z;
#pragma unroll
  for (int i=0;i<16;++i) z[i]=0.f;
  return z; }
DEV f32x16 mfma32(bf16x8 a, bf16x8 b, f32x16 c){ return __builtin_amdgcn_mfma_f32_32x32x16_bf16(a,b,c,0,0,0); }

// ---------------------------------------------------------------------------
// GEMM: C[4096][512] = A @ W + bias.  BM=128, BN=64, BK=64, 4 waves.
// BF32: B is the raw fp32 W [k][n] — transpose+convert fused into staging
// (replaces the standalone wt_kernel; bit-identical f2b values).
// If Xt != nullptr (K/V projections): also emit the head-transposed tile
// Xt[dh][s] via an LDS round-trip epilogue (replaces kvt_kernel).
// ---------------------------------------------------------------------------
template<bool AF32, bool OUTB16>
DEV void gemm_body(const void* A, const float* W, const float* bias, void* C,
                   int m0, int n0, short* Alds, short* Blds, short* Xt){
  const int tid = threadIdx.x, lane = tid&63, wid = tid>>6, lo5 = lane&31, hi = lane>>5;
  f32x16 acc0 = z16(), acc1 = z16();
  for (int kt=0; kt<8; ++kt){
    const int k0 = kt*64;
    __syncthreads();
    {
      const int rr = tid>>3, c = tid&7;
#pragma unroll
      for (int p=0;p<4;++p){
        int row = p*32 + rr;
        short8 v;
        if (AF32){
          const float* ap = (const float*)A + (size_t)(m0+row)*512 + k0 + c*8;
          float4 x = *(const float4*)ap; float4 y = *(const float4*)(ap+4);
          v = short8{ f2b(x.x),f2b(x.y),f2b(x.z),f2b(x.w), f2b(y.x),f2b(y.y),f2b(y.z),f2b(y.w) };
        } else {
          v = *(const short8*)((const short*)A + (size_t)(m0+row)*512 + k0 + c*8);
        }
        *(short8*)&Alds[row*64 + ((c ^ (row&7))*8)] = v;
      }
      // B staging from fp32 W [k][n], transposed into Blds[n][k] (swizzled).
      // thread (r2 = tid>>2: k-row, c4 = tid&3: n-group of 16)
      {
        const int r2 = tid>>2, c4 = tid&3;
        const float* wrow = W + (size_t)(k0+r2)*512 + n0 + c4*16;
        float4 f0 = *(const float4*)(wrow);
        float4 f1 = *(const float4*)(wrow+4);
        float4 f2 = *(const float4*)(wrow+8);
        float4 f3 = *(const float4*)(wrow+12);
        float fv[16] = { f0.x,f0.y,f0.z,f0.w, f1.x,f1.y,f1.z,f1.w,
                         f2.x,f2.y,f2.z,f2.w, f3.x,f3.y,f3.z,f3.w };
        const int kc = r2>>3, ko = r2&7;
#pragma unroll
        for (int e=0;e<16;++e){
          const int n = c4*16 + e;
          Blds[n*64 + ((kc ^ (n&7))*8) + ko] = f2b(fv[e]);
        }
      }
    }
    __syncthreads();
#pragma unroll
    for (int da=0; da<4; ++da){
      const int arow = wid*32 + lo5;
      bf16x8 af = ld8s(&Alds[arow*64 + (((2*da+hi) ^ (arow&7))*8)]);
      const int b0r = lo5, b1r = 32+lo5;
      bf16x8 bf0 = ld8s(&Blds[b0r*64 + (((2*da+hi) ^ (b0r&7))*8)]);
      bf16x8 bf1 = ld8s(&Blds[b1r*64 + (((2*da+hi) ^ (b1r&7))*8)]);
      acc0 = mfma32(af, bf0, acc0);
      acc1 = mfma32(af, bf1, acc1);
    }
  }
  const float bv0 = bias[n0 + lo5], bv1 = bias[n0 + 32 + lo5];
#pragma unroll
  for (int r=0;r<16;++r){
    const int m = m0 + wid*32 + (r&3) + 8*(r>>2) + 4*hi;
    const float v0 = acc0[r] + bv0, v1 = acc1[r] + bv1;
    if (OUTB16){
      ((short*)C)[(size_t)m*512 + n0 + lo5]      = f2b(v0);
      ((short*)C)[(size_t)m*512 + n0 + 32 + lo5] = f2b(v1);
    } else {
      ((float*)C)[(size_t)m*512 + n0 + lo5]      = v0;
      ((float*)C)[(size_t)m*512 + n0 + 32 + lo5] = v1;
    }
  }
  if (Xt){
    __syncthreads();                // all MFMA LDS reads done -> Alds reusable
#pragma unroll
    for (int r=0;r<16;++r){
      const int ml = wid*32 + (r&3) + 8*(r>>2) + 4*hi;
      Alds[ml*64 + lo5]      = f2b(acc0[r] + bv0);
      Alds[ml*64 + 32 + lo5] = f2b(acc1[r] + bv1);
    }
    __syncthreads();
    const int dh = tid & 63, chq = tid >> 6;      // thread owns 32 s of row dh
    short* xrow = Xt + (size_t)dh*2048 + chq*32;
#pragma unroll
    for (int cp=0; cp<4; ++cp){
      short8 t;
#pragma unroll
      for (int e=0;e<8;++e) t[e] = Alds[(chq*32 + cp*8 + e)*64 + dh];
      *(short8*)(xrow + cp*8) = t;
    }
  }
}

struct ProjArgs { const float* A[3]; const float* W[3]; const float* bias[3]; short* C[3]; short* XT[3]; };

__global__ __launch_bounds__(256) void proj_gemm(ProjArgs args){
  __shared__ short Alds[128*64];
  __shared__ short Blds[64*64];
  const int z = blockIdx.z;
  const int m0 = blockIdx.x*128, n0 = blockIdx.y*64;
  short* xt = nullptr;
  if (args.XT[z]){
    const int b = m0>>11, h = n0>>6, s0 = m0&2047;
    xt = args.XT[z] + ((size_t)(b*8+h)*64)*2048 + s0;
  }
  gemm_body<true,true>(args.A[z], args.W[z], args.bias[z], args.C[z],
                       m0, n0, Alds, Blds, xt);
}

__global__ __launch_bounds__(256) void out_gemm(const short* A, const float* W, const float* bias, float* C){
  __shared__ short Alds[128*64];
  __shared__ short Blds[64*64];
  gemm_body<false,false>(A, W, bias, C, blockIdx.x*128, blockIdx.y*64, Alds, Blds, nullptr);
}

// ---------------------------------------------------------------------------
// Merged kv-partial + prefix kernel. Grid = 192 blocks, 256 threads.
//  blk <  128: KVpart[(bh*8+ch)][j*64+i] = Σ_{s in chunk} K[s][i]V[s][j] (fp32)
//  blk >= 128: prefix sums; idx = blk-128: bh=idx>>2, z=(idx>>1)&1, dhalf=idx&1
// ---------------------------------------------------------------------------
__global__ __launch_bounds__(256) void kvpfx_kernel(const short* Kp, const short* Vp,
    const short* Kt, const short* Vt, float* KVpart, float* KP, float* VP){
  __shared__ float shmem[4*64*64];   // 64 KB, aliased per branch
  const int blk = blockIdx.x, tid = threadIdx.x;

  if (blk < 128){
    const int bh = blk>>3, ch = blk&7;
    const int lane = tid&63, wid = tid>>6, lo5 = lane&31, hi = lane>>5;
    const short* Ktb = Kt + (size_t)bh*64*2048;
    const short* Vtb = Vt + (size_t)bh*64*2048;
    f32x16 a00=z16(), a01=z16(), a10=z16(), a11=z16();
    const int sb = ch*256 + wid*64;
    for (int s = sb; s < sb+64; s += 16){
      bf16x8 ka = ld8s(Ktb + (size_t)lo5*2048 + s + hi*8);
      bf16x8 kb = ld8s(Ktb + (size_t)(32+lo5)*2048 + s + hi*8);
      bf16x8 va = ld8s(Vtb + (size_t)lo5*2048 + s + hi*8);
      bf16x8 vb = ld8s(Vtb + (size_t)(32+lo5)*2048 + s + hi*8);
      a00 = mfma32(ka, va, a00);
      a01 = mfma32(ka, vb, a01);
      a10 = mfma32(kb, va, a10);
      a11 = mfma32(kb, vb, a11);
    }
    float (*red)[64][64] = (float(*)[64][64])shmem;
#pragma unroll
    for (int r=0;r<16;++r){
      int ir = (r&3) + 8*(r>>2) + 4*hi;
      red[wid][ir][lo5]        = a00[r];
      red[wid][ir][32+lo5]     = a01[r];
      red[wid][32+ir][lo5]     = a10[r];
      red[wid][32+ir][32+lo5]  = a11[r];
    }
    __syncthreads();
    float* dst = KVpart + (size_t)(bh*8+ch)*4096;
    for (int e = tid; e < 4096; e += 256){
      int j = e>>6, i = e&63;
      dst[e] = red[0][i][j] + red[1][i][j] + red[2][i][j] + red[3][i][j];  // KVpart[j][i]
    }
  } else {
    const int idx = blk - 128;
    const int bh = idx>>2, z = (idx>>1)&1, dhalf = idx&1;
    const int b = bh>>3, h = bh&7;
    const short* X = (z ? Vp : Kp) + (size_t)b*2048*512 + h*64 + dhalf*32;
    float* P = (z ? VP : KP) + (size_t)bh*2048*64 + dhalf*32;
    const int dg = tid & 3;          // d-group within half: d = dg*8..dg*8+7
    const int ch = tid >> 2;         // chunk: rows ch*32 .. +31
    float (*tot)[4][8] = (float(*)[4][8])shmem;  // [64][4][8]

    const short* xp = X + (size_t)(ch*32)*512 + dg*8;
    float acc[8];
#pragma unroll
    for (int j=0;j<8;++j) acc[j]=0.f;
    for (int i=0;i<32;++i){
      short8 v = *(const short8*)(xp + (size_t)i*512);
#pragma unroll
      for (int j=0;j<8;++j) acc[j] += b2f(v[j]);
    }
#pragma unroll
    for (int j=0;j<8;++j) tot[ch][dg][j] = acc[j];
    __syncthreads();

    float run[8];
#pragma unroll
    for (int j=0;j<8;++j) run[j]=0.f;
    for (int cc=0; cc<ch; ++cc){
      float4 a = *(const float4*)&tot[cc][dg][0];
      float4 c4 = *(const float4*)&tot[cc][dg][4];
      run[0]+=a.x; run[1]+=a.y; run[2]+=a.z; run[3]+=a.w;
      run[4]+=c4.x; run[5]+=c4.y; run[6]+=c4.z; run[7]+=c4.w;
    }
    float* pp = P + (size_t)(ch*32)*64 + dg*8;
    for (int i=0;i<32;++i){
      short8 v = *(const short8*)(xp + (size_t)i*512);
#pragma unroll
      for (int j=0;j<8;++j) run[j] += b2f(v[j]);
      float4 o0 = { run[0], run[1], run[2], run[3] };
      float4 o1 = { run[4], run[5], run[6], run[7] };
      *(float4*)(pp + (size_t)i*64)     = o0;
      *(float4*)(pp + (size_t)i*64 + 4) = o1;
    }
  }
}

// ---------------------------------------------------------------------------
// attn2: per (qt, bh) block of 128 q rows, 4 waves x 32 q.
//  Prologue: reduce 8 fp32 KVpart chunks -> swizzled bf16 LDS tile KVl[j][i].
//  w1 = Q·KV + band(Rq)·V + r0*Vpre + r20*Vsuf
//  w2 = CS @ rel_v,  CS[q][j]: j=0 bin0, j=20 bin20 (prefix dots), j=1..19 band
// ---------------------------------------------------------------------------
__global__ __launch_bounds__(256) void attn2_kernel(const short* Qp, const short* Kp,
    const short* Vt, const float* KVpart, const float* KP, const float* VP,
    const float* relk_g, const float* relv_g, short* xb){
  const int qt = blockIdx.x, bh = blockIdx.y;
  const int b = bh>>3, h = bh&7;
  const int tid = threadIdx.x, lane = tid&63, wid = tid>>6, lo5 = lane&31, hi = lane>>5;
  const int q0 = qt*128, qw = q0 + wid*32;

  __shared__ float Rq[128*21];
  __shared__ short CS[128*32];
  __shared__ short RVT[64*32];
  __shared__ short KVl[64*64];

  for (int i=tid; i<2048; i+=256) ((int*)CS)[i] = 0;
  for (int i=tid; i<2048; i+=256){
    int d = i>>5, j = i&31;
    RVT[d*32 + (j ^ ((d&3)<<3))] = (j<21) ? f2b(relv_g[j*64+d]) : (short)0;
  }

  // KV reduction: thread owns (j = tid>>2, i0 = (tid&3)*16); swizzled store
  {
    const int j = tid>>2, i0 = (tid&3)*16;
    float acc[16];
#pragma unroll
    for (int t=0;t<16;++t) acc[t]=0.f;
#pragma unroll
    for (int c=0;c<8;++c){
      const float* p = KVpart + (size_t)(bh*8+c)*4096 + j*64 + i0;
#pragma unroll
      for (int t4=0;t4<4;++t4){
        float4 v = *(const float4*)(p + t4*4);
        acc[t4*4+0]+=v.x; acc[t4*4+1]+=v.y; acc[t4*4+2]+=v.z; acc[t4*4+3]+=v.w;
      }
    }
#pragma unroll
    for (int half=0; half<2; ++half){
      short8 o;
#pragma unroll
      for (int e=0;e<8;++e) o[e] = f2b(acc[half*8+e]);
      const int chunk = (i0>>3) + half;
      *(short8*)&KVl[j*64 + ((chunk ^ (j&7))*8)] = o;
    }
  }

  // Q fragments
  bf16x8 qf[4];
  {
    const short* Qrow = Qp + (size_t)(b*2048 + qw + lo5)*512 + h*64 + hi*8;
#pragma unroll
    for (int da=0;da<4;++da) qf[da] = ld8s(Qrow + da*16);
  }

  // Rq[q][j] = Q[q]·rel_k[j]
  {
    f32x16 rq = z16();
    const int jr = lo5 <= 20 ? lo5 : 20;
    const float* rp = relk_g + jr*64 + hi*8;
#pragma unroll
    for (int da=0;da<4;++da){
      const float* p = rp + da*16;
      float4 x = *(const float4*)p; float4 y = *(const float4*)(p+4);
      short8 rb = { f2b(x.x),f2b(x.y),f2b(x.z),f2b(x.w), f2b(y.x),f2b(y.y),f2b(y.z),f2b(y.w) };
      rq = mfma32(qf[da], __builtin_bit_cast(bf16x8, rb), rq);
    }
    if (lo5 <= 20){
#pragma unroll
      for (int r=0;r<16;++r){
        int qoff = (r&3) + 8*(r>>2) + 4*hi;
        Rq[(wid*32 + qoff)*21 + lo5] = rq[r];
      }
    }
  }
  __syncthreads();

  const int qrow = wid*32 + lo5;
  const int qg = q0 + qrow;

  f32x16 w1a = z16(), w1b = z16();

  // (a) Q·KV from swizzled LDS
  {
#pragma unroll
    for (int c=0;c<4;++c){
      const int r0i = lo5, r1i = 32+lo5, ck = 2*c+hi;
      bf16x8 b0v = ld8s(&KVl[r0i*64 + ((ck ^ (r0i&7))*8)]);
      bf16x8 b1v = ld8s(&KVl[r1i*64 + ((ck ^ (r1i&7))*8)]);
      w1a = mfma32(qf[c], b0v, w1a);
      w1b = mfma32(qf[c], b1v, w1b);
    }
  }

  // (b) band-PV
  {
    const short* Vg = Vt + (size_t)bh*64*2048;
#pragma unroll
    for (int c=0;c<4;++c){
      const int kb = qw - 16 + c*16;
      const int kbse = kb + hi*8;
      const int jb = kbse - (qw + lo5) + 10;
      short8 av;
#pragma unroll
      for (int e=0;e<8;++e){
        int j = jb + e, kk = kbse + e;
        int jc = j < 1 ? 1 : (j > 19 ? 19 : j);
        float rv = Rq[qrow*21 + jc];
        bool ok = (j>=1) && (j<=19) && (kk>=0) && (kk<2048);
        av[e] = ok ? f2b(rv) : (short)0;
      }
      bf16x8 af = __builtin_bit_cast(bf16x8, av);
      const int kc = kb < 0 ? 0 : (kb > 2048-16 ? 2048-16 : kb);
      bf16x8 v0 = ld8s(Vg + (size_t)lo5*2048 + kc + hi*8);
      bf16x8 v1 = ld8s(Vg + (size_t)(32+lo5)*2048 + kc + hi*8);
      w1a = mfma32(af, v0, w1a);
      w1b = mfma32(af, v1, w1b);
    }
  }

  // (c) prefix-V terms
  {
    const float* VPb = VP + (size_t)bh*2048*64;
    const float vt0 = VPb[(size_t)2047*64 + lo5];
    const float vt1 = VPb[(size_t)2047*64 + 32 + lo5];
#pragma unroll
    for (int r=0;r<16;++r){
      const int q_r = qw + (r&3) + 8*(r>>2) + 4*hi;
      const int ql = q_r - q0;
      const float r0q  = Rq[ql*21 + 0];
      const float r20q = Rq[ql*21 + 20];
      float p0=0.f, p1=0.f, s0=0.f, s1=0.f;
      if (q_r >= 10){
        const float* pr = VPb + (size_t)(q_r-10)*64;
        p0 = pr[lo5]; p1 = pr[32+lo5];
      }
      if (q_r <= 2037){
        const float* sr = VPb + (size_t)(q_r+9)*64;
        s0 = vt0 - sr[lo5]; s1 = vt1 - sr[32+lo5];
      }
      w1a[r] += r0q*p0 + r20q*s0;
      w1b[r] += r0q*p1 + r20q*s1;
    }
  }

  // (d) diagonal QK^T subtiles -> CS band (j=1..19)
  {
    const short* Kg = Kp + (size_t)b*2048*512 + h*64;
#pragma unroll
    for (int t3=0; t3<3; ++t3){
      const int kb = qw - 32 + t3*32;
      if (kb < 0 || kb >= 2048) continue;
      const short* Krow = Kg + (size_t)(kb + lo5)*512 + hi*8;
      f32x16 acc = z16();
#pragma unroll
      for (int da=0;da<4;++da) acc = mfma32(ld8s(Krow + da*16), qf[da], acc);
#pragma unroll
      for (int r=0;r<16;++r){
        const int krow = kb + (r&3) + 8*(r>>2) + 4*hi;
        const int j = krow - qg + 10;
        if (j >= 1 && j <= 19)
          CS[qrow*32 + (j ^ ((qrow&3)<<3))] = f2b(acc[r] + Rq[qrow*21 + j]);
      }
    }
  }

  // (e) bins via K-prefix dots; wave-uniform split (waves 0-1: bin0, 2-3: bin20)
  {
    const int half = tid >> 7, q_loc = tid & 127;
    const int q_g2 = q0 + q_loc;
    const short* Qr = Qp + (size_t)(b*2048 + q_g2)*512 + h*64;
    const float* KPb = KP + (size_t)bh*2048*64;
    float val = 0.f;
    if (half == 0){
      if (q_g2 >= 10){
        const float* Pr = KPb + (size_t)(q_g2-10)*64;
        float dot = 0.f;
#pragma unroll
        for (int ii=0; ii<8; ++ii){
          short8 qv = *(const short8*)(Qr + ii*8);
          float4 p0 = *(const float4*)(Pr + ii*8);
          float4 p1 = *(const float4*)(Pr + ii*8 + 4);
          dot += b2f(qv[0])*p0.x + b2f(qv[1])*p0.y + b2f(qv[2])*p0.z + b2f(qv[3])*p0.w
               + b2f(qv[4])*p1.x + b2f(qv[5])*p1.y + b2f(qv[6])*p1.z + b2f(qv[7])*p1.w;
        }
        val = dot + (float)(q_g2 - 9) * Rq[q_loc*21 + 0];
      }
      CS[q_loc*32 + (0 ^ ((q_loc&3)<<3))] = f2b(val);
    } else {
      if (q_g2 <= 2037){
        const float* Pt = KPb + (size_t)2047*64;
        const float* Pr = KPb + (size_t)(q_g2+9)*64;
        float dot = 0.f;
#pragma unroll
        for (int ii=0; ii<8; ++ii){
          short8 qv = *(const short8*)(Qr + ii*8);
          float4 p0 = *(const float4*)(Pr + ii*8);
          float4 t0 = *(const float4*)(Pt + ii*8);
          float4 p1 = *(const float4*)(Pr + ii*8 + 4);
          float4 t1 = *(const float4*)(Pt + ii*8 + 4);
          dot += b2f(qv[0])*(t0.x-p0.x) + b2f(qv[1])*(t0.y-p0.y)
               + b2f(qv[2])*(t0.z-p0.z) + b2f(qv[3])*(t0.w-p0.w)
               + b2f(qv[4])*(t1.x-p1.x) + b2f(qv[5])*(t1.y-p1.y)
               + b2f(qv[6])*(t1.z-p1.z) + b2f(qv[7])*(t1.w-p1.w);
        }
        val = dot + (float)(2038 - q_g2) * Rq[q_loc*21 + 20];
      }
      CS[q_loc*32 + (20 ^ ((q_loc&3)<<3))] = f2b(val);
    }
  }
  __syncthreads();

  // (f) w2 = CS @ RVT
  f32x16 w2a = z16(), w2b = z16();
#pragma unroll
  for (int c2=0;c2<2;++c2){
    const int arow = wid*32 + lo5;
    bf16x8 cf  = ld8s(&CS[arow*32 + ((16*c2 + 8*hi) ^ ((arow&3)<<3))]);
    const int d0 = lo5, d1 = 32 + lo5;
    bf16x8 rv0 = ld8s(&RVT[d0*32 + ((16*c2 + 8*hi) ^ ((d0&3)<<3))]);
    bf16x8 rv1 = ld8s(&RVT[d1*32 + ((16*c2 + 8*hi) ^ ((d1&3)<<3))]);
    w2a = mfma32(cf, rv0, w2a);
    w2b = mfma32(cf, rv1, w2b);
  }

  // (g) write xb
#pragma unroll
  for (int r=0;r<16;++r){
    const int q_r = qw + (r&3) + 8*(r>>2) + 4*hi;
    const size_t o = ((size_t)b*2048 + q_r)*512 + h*64;
    xb[o + lo5]      = f2b((w1a[r] + w2a[r]) * INV_SCALE);
    xb[o + 32 + lo5] = f2b((w1b[r] + w2b[r]) * INV_SCALE);
  }
}

// ---------------------------------------------------------------------------
extern "C" void kernel_launch(void* const* d_in, const int* in_sizes, int n_in,
                              void* d_out, int out_size, void* d_ws, size_t ws_size,
                              hipStream_t stream) {
  (void)in_sizes; (void)n_in; (void)out_size; (void)ws_size;
  const float* q    = (const float*)d_in[0];
  const float* k    = (const float*)d_in[1];
  const float* v    = (const float*)d_in[2];
  // d_in[3] = mask (no-op)
  const float* Wq   = (const float*)d_in[4];
  const float* bq   = (const float*)d_in[5];
  const float* Wk   = (const float*)d_in[6];
  const float* bk   = (const float*)d_in[7];
  const float* Wv   = (const float*)d_in[8];
  const float* bv   = (const float*)d_in[9];
  const float* W0   = (const float*)d_in[10];
  const float* b0   = (const float*)d_in[11];
  const float* relk = (const float*)d_in[12];
  const float* relv = (const float*)d_in[13];
  float* out = (float*)d_out;
  char* ws = (char*)d_ws;

  short* Qp  = (short*)(ws + ((size_t) 2<<20));
  short* Kp  = (short*)(ws + ((size_t) 6<<20));
  short* Vp  = (short*)(ws + ((size_t)10<<20));
  short* Vt  = (short*)(ws + ((size_t)14<<20));
  short* Kt  = (short*)(ws + ((size_t)18<<20));
  float* KVpart = (float*)(ws + ((size_t)22<<20)); // 2 MB (128 x 4096 fp32)
  float* KP  = (float*)(ws + ((size_t)24<<20));    // 8 MB
  float* VP  = (float*)(ws + ((size_t)32<<20));    // 8 MB
  short* xb  = (short*)(ws + ((size_t)40<<20));    // 4 MB

  ProjArgs pa = { {q, k, v}, {Wq, Wk, Wv}, {bq, bk, bv}, {Qp, Kp, Vp},
                  {nullptr, Kt, Vt} };
  proj_gemm<<<dim3(32,8,3), 256, 0, stream>>>(pa);

  kvpfx_kernel<<<192, 256, 0, stream>>>(Kp, Vp, Kt, Vt, KVpart, KP, VP);

  attn2_kernel<<<dim3(16,16), 256, 0, stream>>>(Qp, Kp, Vt, KVpart, KP, VP, relk, relv, xb);

  out_gemm<<<dim3(32,8), 256, 0, stream>>>(xb, W0, b0, out);
}